// Round 1
// baseline (804.622 us; speedup 1.0000x reference)
//
#include <hip/hip_runtime.h>
#include <hip/hip_bf16.h>

#define NTOK 2048
#define DIM 512
#define HID 2048
#define NEXP 64
#define NSLICE 8
#define HSLICE 256   // HID / NSLICE
#define TT 64        // token tile per pass
#define LN_EPS 1e-5f

typedef __bf16 bf16x8 __attribute__((ext_vector_type(8)));
typedef float f32x4 __attribute__((ext_vector_type(4)));

// ---------------- init: zero accumulator + counts ----------------
__global__ void init_kernel(float4* __restrict__ accb, int* __restrict__ counts) {
    int i = blockIdx.x * blockDim.x + threadIdx.x;   // 1024*256 = 262144 = NTOK*DIM/4
    accb[i] = make_float4(0.f, 0.f, 0.f, 0.f);
    if (i < NEXP) counts[i] = 0;
}

// ---------------- gating: softmax + top2 + bucket ----------------
__global__ void gate_kernel(const float* __restrict__ x,
                            const float* __restrict__ Wg,
                            const float* __restrict__ bg,
                            int* __restrict__ counts,
                            int* __restrict__ btok,
                            float* __restrict__ bw) {
    const int t = blockIdx.x;
    const int lane = threadIdx.x;  // 64 threads = 1 wave
    __shared__ float xs[DIM];
    const float4* xrow = (const float4*)(x + (size_t)t * DIM);
    ((float4*)xs)[lane] = xrow[lane];
    ((float4*)xs)[lane + 64] = xrow[lane + 64];
    __syncthreads();

    float acc = bg[lane];
    #pragma unroll 8
    for (int d = 0; d < DIM; d++) acc += xs[d] * Wg[d * NEXP + lane];

    // wave softmax over 64 experts
    float m = acc;
    #pragma unroll
    for (int off = 32; off; off >>= 1) m = fmaxf(m, __shfl_xor(m, off));
    float p = __expf(acc - m);
    float ssum = p;
    #pragma unroll
    for (int off = 32; off; off >>= 1) ssum += __shfl_xor(ssum, off);
    float prob = p / ssum;

    // top-1 (argmax, tie -> lower index)
    float v1 = prob; int i1 = lane;
    #pragma unroll
    for (int off = 32; off; off >>= 1) {
        float ov = __shfl_xor(v1, off);
        int   oi = __shfl_xor(i1, off);
        if (ov > v1 || (ov == v1 && oi < i1)) { v1 = ov; i1 = oi; }
    }
    // top-2
    float v2 = (lane == i1) ? -1e30f : prob; int i2 = lane;
    #pragma unroll
    for (int off = 32; off; off >>= 1) {
        float ov = __shfl_xor(v2, off);
        int   oi = __shfl_xor(i2, off);
        if (ov > v2 || (ov == v2 && oi < i2)) { v2 = ov; i2 = oi; }
    }

    if (lane == 0) {
        int s0 = atomicAdd(&counts[i1], 1);
        btok[i1 * NTOK + s0] = t;  bw[i1 * NTOK + s0] = v1;
        int s1 = atomicAdd(&counts[i2], 1);
        btok[i2 * NTOK + s1] = t;  bw[i2 * NTOK + s1] = v2;
    }
}

// ---------------- grouped FFN: per (expert, H-slice) block ----------------
// LDS: Xs = 64 tok x 256 k bf16 (32KB, K-chunked), Hs = 64 tok x 256 h bf16 (32KB)
// XOR swizzle on 16B chunks: chunk kc of row t stored at (kc ^ (t&7))
__global__ __launch_bounds__(256, 2) void ffn_kernel(
    const float* __restrict__ x,
    const float* __restrict__ W1, const float* __restrict__ b1,
    const float* __restrict__ W2, const float* __restrict__ b2,
    const int* __restrict__ counts,
    const int* __restrict__ btok, const float* __restrict__ bw,
    float* __restrict__ accb)
{
    extern __shared__ char smem[];                // 65536 bytes
    const int e = blockIdx.x >> 3;
    const int s = blockIdx.x & 7;
    const int n = counts[e];
    if (n <= 0) return;

    const int tid  = threadIdx.x;
    const int lane = tid & 63;
    const int wid  = tid >> 6;
    const int lq   = lane >> 4;                   // quad 0..3
    const int lm   = lane & 15;

    const float* W1e = W1 + (size_t)e * DIM * HID;
    const float* W2e = W2 + (size_t)e * HID * DIM;
    const int*   btoke = btok + e * NTOK;
    const float* bwe   = bw   + e * NTOK;

    for (int t0 = 0; t0 < n; t0 += TT) {
        const int tiln = min(TT, n - t0);

        // ---- Phase A: h[64 x 256] = relu(X @ W1slice + b1) ----
        f32x4 acc[4][4];                          // [nt][mt]
        #pragma unroll
        for (int i = 0; i < 4; i++)
            #pragma unroll
            for (int j = 0; j < 4; j++) acc[i][j] = (f32x4)0.0f;

        for (int kc2 = 0; kc2 < 2; kc2++) {       // K=512 in 2 chunks of 256
            const int kbase = kc2 * 256;
            __syncthreads();                       // prev readers of Xs/Hs done
            // stage Xs: 2048 16B-chunks, 8 bf16 each
            #pragma unroll
            for (int it = 0; it < 8; it++) {
                int ci = it * 256 + tid;
                int tr = ci >> 5;                  // token row 0..63
                int kc = ci & 31;                  // 16B chunk in row
                char* dst = smem + tr * 512 + ((kc ^ (tr & 7)) * 16);
                if (tr < tiln) {
                    const float* xp = x + (size_t)btoke[t0 + tr] * DIM + kbase + kc * 8;
                    float4 f0 = *(const float4*)(xp);
                    float4 f1 = *(const float4*)(xp + 4);
                    bf16x8 v;
                    v[0]=(__bf16)f0.x; v[1]=(__bf16)f0.y; v[2]=(__bf16)f0.z; v[3]=(__bf16)f0.w;
                    v[4]=(__bf16)f1.x; v[5]=(__bf16)f1.y; v[6]=(__bf16)f1.z; v[7]=(__bf16)f1.w;
                    *(bf16x8*)dst = v;
                } else {
                    bf16x8 z = (bf16x8)0.0f;
                    *(bf16x8*)dst = z;
                }
            }
            __syncthreads();

            for (int ks = 0; ks < 8; ks++) {       // 8 k-steps of 32
                bf16x8 af[4];
                int kcA = ks * 4 + lq;
                #pragma unroll
                for (int mt = 0; mt < 4; mt++) {
                    int tr = mt * 16 + lm;
                    af[mt] = *(const bf16x8*)(smem + tr * 512 + ((kcA ^ (tr & 7)) * 16));
                }
                int kk = kbase + ks * 32 + lq * 8; // global k for j=0
                #pragma unroll
                for (int nt = 0; nt < 4; nt++) {
                    int hglob = s * HSLICE + wid * 64 + nt * 16 + lm;
                    const float* wp = W1e + (size_t)kk * HID + hglob;
                    bf16x8 bfv;
                    #pragma unroll
                    for (int j = 0; j < 8; j++) bfv[j] = (__bf16)wp[(size_t)j * HID];
                    #pragma unroll
                    for (int mt = 0; mt < 4; mt++)
                        acc[nt][mt] = __builtin_amdgcn_mfma_f32_16x16x32_bf16(
                            af[mt], bfv, acc[nt][mt], 0, 0, 0);
                }
            }
        }

        // relu + b1 -> Hs (bf16, same swizzle)
        #pragma unroll
        for (int nt = 0; nt < 4; nt++) {
            int hloc0 = wid * 64 + nt * 16 + lm;
            float b1v = b1[e * HID + s * HSLICE + hloc0];
            #pragma unroll
            for (int mt = 0; mt < 4; mt++) {
                #pragma unroll
                for (int r = 0; r < 4; r++) {
                    int tr = mt * 16 + lq * 4 + r;
                    float v = fmaxf(acc[nt][mt][r] + b1v, 0.f);
                    *(__bf16*)(smem + 32768 + tr * 512 +
                               (((hloc0 >> 3) ^ (tr & 7)) * 16) + (hloc0 & 7) * 2) = (__bf16)v;
                }
            }
        }
        __syncthreads();

        // ---- Phase B: Y[64 x 512] = Hs @ W2slice, atomic combine ----
        for (int ch = 0; ch < 2; ch++) {           // N=512 in 2 chunks of 64/wave... (wave covers 128: 2x64)
            f32x4 yacc[4][4];
            #pragma unroll
            for (int i = 0; i < 4; i++)
                #pragma unroll
                for (int j = 0; j < 4; j++) yacc[i][j] = (f32x4)0.0f;

            for (int ks = 0; ks < 8; ks++) {
                bf16x8 af[4];
                int kcA = ks * 4 + lq;
                #pragma unroll
                for (int mt = 0; mt < 4; mt++) {
                    int tr = mt * 16 + lm;
                    af[mt] = *(const bf16x8*)(smem + 32768 + tr * 512 + ((kcA ^ (tr & 7)) * 16));
                }
                int hh = s * HSLICE + ks * 32 + lq * 8;
                #pragma unroll
                for (int nt = 0; nt < 4; nt++) {
                    int d = wid * 128 + ch * 64 + nt * 16 + lm;
                    const float* wp = W2e + (size_t)hh * DIM + d;
                    bf16x8 bfv;
                    #pragma unroll
                    for (int j = 0; j < 8; j++) bfv[j] = (__bf16)wp[(size_t)j * DIM];
                    #pragma unroll
                    for (int mt = 0; mt < 4; mt++)
                        yacc[nt][mt] = __builtin_amdgcn_mfma_f32_16x16x32_bf16(
                            af[mt], bfv, yacc[nt][mt], 0, 0, 0);
                }
            }
            // epilogue
            float b2s[4];
            #pragma unroll
            for (int nt = 0; nt < 4; nt++) {
                int d = wid * 128 + ch * 64 + nt * 16 + lm;
                b2s[nt] = (s == 0) ? b2[e * DIM + d] : 0.f;
            }
            #pragma unroll
            for (int mt = 0; mt < 4; mt++) {
                #pragma unroll
                for (int r = 0; r < 4; r++) {
                    int tr = mt * 16 + lq * 4 + r;
                    if (tr < tiln) {
                        int tok = btoke[t0 + tr];
                        float w = bwe[t0 + tr];
                        float* dst = accb + (size_t)tok * DIM;
                        #pragma unroll
                        for (int nt = 0; nt < 4; nt++) {
                            int d = wid * 128 + ch * 64 + nt * 16 + lm;
                            atomicAdd(dst + d, w * (yacc[nt][mt][r] + b2s[nt]));
                        }
                    }
                }
            }
        }
    }
}

// ---------------- residual + LayerNorm ----------------
__global__ void ln_kernel(const float* __restrict__ x,
                          const float* __restrict__ accb,
                          const float* __restrict__ gamma,
                          const float* __restrict__ beta,
                          float* __restrict__ out) {
    const int t = blockIdx.x;
    const int tid = threadIdx.x;                  // 256
    __shared__ float red[8];
    const size_t base = (size_t)t * DIM;
    float v0 = x[base + tid] + accb[base + tid];
    float v1 = x[base + 256 + tid] + accb[base + 256 + tid];
    float s  = v0 + v1;
    float sq = v0 * v0 + v1 * v1;
    #pragma unroll
    for (int off = 32; off; off >>= 1) { s += __shfl_xor(s, off); sq += __shfl_xor(sq, off); }
    if ((tid & 63) == 0) { red[tid >> 6] = s; red[4 + (tid >> 6)] = sq; }
    __syncthreads();
    float S  = red[0] + red[1] + red[2] + red[3];
    float SQ = red[4] + red[5] + red[6] + red[7];
    float mu  = S * (1.f / DIM);
    float var = SQ * (1.f / DIM) - mu * mu;
    float inv = rsqrtf(var + LN_EPS);
    out[base + tid]       = (v0 - mu) * inv * gamma[tid]       + beta[tid];
    out[base + 256 + tid] = (v1 - mu) * inv * gamma[256 + tid] + beta[256 + tid];
}

extern "C" void kernel_launch(void* const* d_in, const int* in_sizes, int n_in,
                              void* d_out, int out_size, void* d_ws, size_t ws_size,
                              hipStream_t stream) {
    const float* x     = (const float*)d_in[0];
    const float* Wg    = (const float*)d_in[1];
    const float* bg    = (const float*)d_in[2];
    const float* W1    = (const float*)d_in[3];
    const float* b1    = (const float*)d_in[4];
    const float* W2    = (const float*)d_in[5];
    const float* b2    = (const float*)d_in[6];
    const float* gamma = (const float*)d_in[7];
    const float* beta  = (const float*)d_in[8];

    char* ws = (char*)d_ws;
    int*   counts = (int*)ws;                                  // 256 B
    int*   btok   = (int*)(ws + 4096);                          // 512 KB
    float* bwv    = (float*)(ws + 4096 + 524288);               // 512 KB
    float* accb   = (float*)(ws + 4096 + 2 * 524288);           // 4 MB

    init_kernel<<<1024, 256, 0, stream>>>((float4*)accb, counts);
    gate_kernel<<<NTOK, 64, 0, stream>>>(x, Wg, bg, counts, btok, bwv);
    ffn_kernel<<<NEXP * NSLICE, 256, 65536, stream>>>(x, W1, b1, W2, b2,
                                                      counts, btok, bwv, accb);
    ln_kernel<<<NTOK, 256, 0, stream>>>(x, accb, gamma, beta, (float*)d_out);
}

// Round 2
// 746.954 us; speedup vs baseline: 1.0772x; 1.0772x over previous
//
#include <hip/hip_runtime.h>
#include <hip/hip_bf16.h>

#define NTOK 2048
#define DIM 512
#define HID 2048
#define NEXP 64
#define NSLICE 8
#define HSLICE 256   // HID / NSLICE
#define TT 64        // token tile per pass
#define LN_EPS 1e-5f

// LDS layout (bytes):
//   [0, 20480)         Ws  : weight stage, 256 rows x (4x16B + 16B pad) = 80B/row
//   [20480, 53248)     Hs  : 64 tok x 256 h bf16, row 512B, xor-swizzled 16B chunks
#define WS_OFF 0
#define HS_OFF 20480
#define SMEM_BYTES 53248

typedef __bf16 bf16x8 __attribute__((ext_vector_type(8)));
typedef float f32x4 __attribute__((ext_vector_type(4)));

// ---------------- init: zero accumulator + counts ----------------
__global__ void init_kernel(float4* __restrict__ accb, int* __restrict__ counts) {
    int i = blockIdx.x * blockDim.x + threadIdx.x;
    accb[i] = make_float4(0.f, 0.f, 0.f, 0.f);
    if (i < NEXP) counts[i] = 0;
}

// ---------------- gating: softmax + top2 + bucket ----------------
__global__ void gate_kernel(const float* __restrict__ x,
                            const float* __restrict__ Wg,
                            const float* __restrict__ bg,
                            int* __restrict__ counts,
                            int* __restrict__ btok,
                            float* __restrict__ bw) {
    const int t = blockIdx.x;
    const int lane = threadIdx.x;  // 64 threads = 1 wave
    __shared__ float xs[DIM];
    const float4* xrow = (const float4*)(x + (size_t)t * DIM);
    ((float4*)xs)[lane] = xrow[lane];
    ((float4*)xs)[lane + 64] = xrow[lane + 64];
    __syncthreads();

    float acc = bg[lane];
    #pragma unroll 8
    for (int d = 0; d < DIM; d++) acc += xs[d] * Wg[d * NEXP + lane];

    float m = acc;
    #pragma unroll
    for (int off = 32; off; off >>= 1) m = fmaxf(m, __shfl_xor(m, off));
    float p = __expf(acc - m);
    float ssum = p;
    #pragma unroll
    for (int off = 32; off; off >>= 1) ssum += __shfl_xor(ssum, off);
    float prob = p / ssum;

    float v1 = prob; int i1 = lane;
    #pragma unroll
    for (int off = 32; off; off >>= 1) {
        float ov = __shfl_xor(v1, off);
        int   oi = __shfl_xor(i1, off);
        if (ov > v1 || (ov == v1 && oi < i1)) { v1 = ov; i1 = oi; }
    }
    float v2 = (lane == i1) ? -1e30f : prob; int i2 = lane;
    #pragma unroll
    for (int off = 32; off; off >>= 1) {
        float ov = __shfl_xor(v2, off);
        int   oi = __shfl_xor(i2, off);
        if (ov > v2 || (ov == v2 && oi < i2)) { v2 = ov; i2 = oi; }
    }

    if (lane == 0) {
        int s0 = atomicAdd(&counts[i1], 1);
        btok[i1 * NTOK + s0] = t;  bw[i1 * NTOK + s0] = v1;
        int s1 = atomicAdd(&counts[i2], 1);
        btok[i2 * NTOK + s1] = t;  bw[i2 * NTOK + s1] = v2;
    }
}

// Stage a 32(k) x 256(col) fp32 tile (row stride rs) into Ws as bf16.
// Thread tid owns column tid; 32 independent coalesced dword loads.
// Ws row layout: col*40 bf16 (80B), 4 groups of bf16x8 (k-contiguous) + pad.
__device__ __forceinline__ void stage_w(const float* __restrict__ src, size_t rs,
                                        __bf16* __restrict__ wsb, int tid) {
    #pragma unroll
    for (int kh = 0; kh < 2; kh++) {
        float v[16];
        #pragma unroll
        for (int u = 0; u < 16; u++)
            v[u] = src[(size_t)(kh * 16 + u) * rs + tid];
        #pragma unroll
        for (int kg = 0; kg < 2; kg++) {
            bf16x8 pk;
            #pragma unroll
            for (int j = 0; j < 8; j++) pk[j] = (__bf16)v[kg * 8 + j];
            *(bf16x8*)(wsb + tid * 40 + (kh * 2 + kg) * 8) = pk;
        }
    }
}

// ---------------- grouped FFN: per (expert, H-slice) block ----------------
__global__ __launch_bounds__(256, 3) void ffn_kernel(
    const float* __restrict__ x,
    const float* __restrict__ W1, const float* __restrict__ b1,
    const float* __restrict__ W2, const float* __restrict__ b2,
    const int* __restrict__ counts,
    const int* __restrict__ btok, const float* __restrict__ bw,
    float* __restrict__ accb)
{
    __shared__ char smem[SMEM_BYTES];
    __bf16* wsb = (__bf16*)(smem + WS_OFF);

    const int e = blockIdx.x >> 3;
    const int s = blockIdx.x & 7;
    const int n = counts[e];
    if (n <= 0) return;

    const int tid  = threadIdx.x;
    const int lane = tid & 63;
    const int wid  = tid >> 6;
    const int lq   = lane >> 4;                   // quad 0..3
    const int lm   = lane & 15;

    const float* W1e = W1 + (size_t)e * DIM * HID;
    const float* W2e = W2 + (size_t)e * HID * DIM;
    const int*   btoke = btok + e * NTOK;
    const float* bwe   = bw   + e * NTOK;

    for (int t0 = 0; t0 < n; t0 += TT) {
        const int tiln = min(TT, n - t0);

        // per-lane A-row tokens (rows mt*16+lm)
        int  toks[4];
        bool tv[4];
        #pragma unroll
        for (int mt = 0; mt < 4; mt++) {
            int tr = mt * 16 + lm;
            tv[mt] = tr < tiln;
            toks[mt] = tv[mt] ? btoke[t0 + tr] : 0;
        }

        // ---- Phase A: h[64 x 256] = relu(X @ W1slice + b1) ----
        f32x4 acc[4][4];                          // [nt][mt]
        #pragma unroll
        for (int i = 0; i < 4; i++)
            #pragma unroll
            for (int j = 0; j < 4; j++) acc[i][j] = (f32x4)0.0f;

        for (int ks = 0; ks < 16; ks++) {         // K=512, 32 per step
            __syncthreads();                       // prev readers of Ws done
            stage_w(W1e + (size_t)(ks * 32) * HID + s * HSLICE, HID, wsb, tid);
            __syncthreads();

            // A frags straight from global (x is L2/L3-resident)
            bf16x8 af[4];
            #pragma unroll
            for (int mt = 0; mt < 4; mt++) {
                if (tv[mt]) {
                    const float* xp = x + (size_t)toks[mt] * DIM + ks * 32 + lq * 8;
                    float4 f0 = *(const float4*)(xp);
                    float4 f1 = *(const float4*)(xp + 4);
                    bf16x8 v;
                    v[0]=(__bf16)f0.x; v[1]=(__bf16)f0.y; v[2]=(__bf16)f0.z; v[3]=(__bf16)f0.w;
                    v[4]=(__bf16)f1.x; v[5]=(__bf16)f1.y; v[6]=(__bf16)f1.z; v[7]=(__bf16)f1.w;
                    af[mt] = v;
                } else {
                    af[mt] = (bf16x8)0.0f;
                }
            }
            #pragma unroll
            for (int nt = 0; nt < 4; nt++) {
                bf16x8 bfv = *(const bf16x8*)(wsb + (wid * 64 + nt * 16 + lm) * 40 + lq * 8);
                #pragma unroll
                for (int mt = 0; mt < 4; mt++)
                    acc[nt][mt] = __builtin_amdgcn_mfma_f32_16x16x32_bf16(
                        af[mt], bfv, acc[nt][mt], 0, 0, 0);
            }
        }

        // relu + b1 -> Hs (bf16, xor-swizzled)
        __syncthreads();
        #pragma unroll
        for (int nt = 0; nt < 4; nt++) {
            int hloc0 = wid * 64 + nt * 16 + lm;
            float b1v = b1[e * HID + s * HSLICE + hloc0];
            #pragma unroll
            for (int mt = 0; mt < 4; mt++) {
                #pragma unroll
                for (int r = 0; r < 4; r++) {
                    int tr = mt * 16 + lq * 4 + r;
                    float v = fmaxf(acc[nt][mt][r] + b1v, 0.f);
                    *(__bf16*)(smem + HS_OFF + tr * 512 +
                               (((hloc0 >> 3) ^ (tr & 7)) * 16) + (hloc0 & 7) * 2) = (__bf16)v;
                }
            }
        }

        // ---- Phase B: Y[64 x 512] = Hs @ W2slice, atomic combine ----
        for (int dh = 0; dh < 2; dh++) {           // D=512 in 2 halves of 256
            f32x4 yacc[4][4];
            #pragma unroll
            for (int i = 0; i < 4; i++)
                #pragma unroll
                for (int j = 0; j < 4; j++) yacc[i][j] = (f32x4)0.0f;

            for (int ks = 0; ks < 8; ks++) {       // 256 h in 8 steps of 32
                __syncthreads();
                stage_w(W2e + (size_t)(s * HSLICE + ks * 32) * DIM + dh * 256, DIM, wsb, tid);
                __syncthreads();

                bf16x8 af[4];
                int kcA = ks * 4 + lq;
                #pragma unroll
                for (int mt = 0; mt < 4; mt++) {
                    int tr = mt * 16 + lm;
                    af[mt] = *(const bf16x8*)(smem + HS_OFF + tr * 512 + ((kcA ^ (tr & 7)) * 16));
                }
                #pragma unroll
                for (int nt = 0; nt < 4; nt++) {
                    bf16x8 bfv = *(const bf16x8*)(wsb + (wid * 64 + nt * 16 + lm) * 40 + lq * 8);
                    #pragma unroll
                    for (int mt = 0; mt < 4; mt++)
                        yacc[nt][mt] = __builtin_amdgcn_mfma_f32_16x16x32_bf16(
                            af[mt], bfv, yacc[nt][mt], 0, 0, 0);
                }
            }
            // epilogue: weighted atomic combine
            float b2s[4];
            #pragma unroll
            for (int nt = 0; nt < 4; nt++) {
                int d = dh * 256 + wid * 64 + nt * 16 + lm;
                b2s[nt] = (s == 0) ? b2[e * DIM + d] : 0.f;
            }
            #pragma unroll
            for (int mt = 0; mt < 4; mt++) {
                #pragma unroll
                for (int r = 0; r < 4; r++) {
                    int tr = mt * 16 + lq * 4 + r;
                    if (tr < tiln) {
                        int tok = btoke[t0 + tr];
                        float w = bwe[t0 + tr];
                        float* dst = accb + (size_t)tok * DIM;
                        #pragma unroll
                        for (int nt = 0; nt < 4; nt++) {
                            int d = dh * 256 + wid * 64 + nt * 16 + lm;
                            atomicAdd(dst + d, w * (yacc[nt][mt][r] + b2s[nt]));
                        }
                    }
                }
            }
        }
        __syncthreads();   // protect Hs before next tile's phase A epilogue
    }
}

// ---------------- residual + LayerNorm ----------------
__global__ void ln_kernel(const float* __restrict__ x,
                          const float* __restrict__ accb,
                          const float* __restrict__ gamma,
                          const float* __restrict__ beta,
                          float* __restrict__ out) {
    const int t = blockIdx.x;
    const int tid = threadIdx.x;                  // 256
    __shared__ float red[8];
    const size_t base = (size_t)t * DIM;
    float v0 = x[base + tid] + accb[base + tid];
    float v1 = x[base + 256 + tid] + accb[base + 256 + tid];
    float s  = v0 + v1;
    float sq = v0 * v0 + v1 * v1;
    #pragma unroll
    for (int off = 32; off; off >>= 1) { s += __shfl_xor(s, off); sq += __shfl_xor(sq, off); }
    if ((tid & 63) == 0) { red[tid >> 6] = s; red[4 + (tid >> 6)] = sq; }
    __syncthreads();
    float S  = red[0] + red[1] + red[2] + red[3];
    float SQ = red[4] + red[5] + red[6] + red[7];
    float mu  = S * (1.f / DIM);
    float var = SQ * (1.f / DIM) - mu * mu;
    float inv = rsqrtf(var + LN_EPS);
    out[base + tid]       = (v0 - mu) * inv * gamma[tid]       + beta[tid];
    out[base + 256 + tid] = (v1 - mu) * inv * gamma[256 + tid] + beta[256 + tid];
}

extern "C" void kernel_launch(void* const* d_in, const int* in_sizes, int n_in,
                              void* d_out, int out_size, void* d_ws, size_t ws_size,
                              hipStream_t stream) {
    const float* x     = (const float*)d_in[0];
    const float* Wg    = (const float*)d_in[1];
    const float* bg    = (const float*)d_in[2];
    const float* W1    = (const float*)d_in[3];
    const float* b1    = (const float*)d_in[4];
    const float* W2    = (const float*)d_in[5];
    const float* b2    = (const float*)d_in[6];
    const float* gamma = (const float*)d_in[7];
    const float* beta  = (const float*)d_in[8];

    char* ws = (char*)d_ws;
    int*   counts = (int*)ws;                                  // 256 B
    int*   btok   = (int*)(ws + 4096);                          // 512 KB
    float* bwv    = (float*)(ws + 4096 + 524288);               // 512 KB
    float* accb   = (float*)(ws + 4096 + 2 * 524288);           // 4 MB

    init_kernel<<<1024, 256, 0, stream>>>((float4*)accb, counts);
    gate_kernel<<<NTOK, 64, 0, stream>>>(x, Wg, bg, counts, btok, bwv);
    ffn_kernel<<<NEXP * NSLICE, 256, 0, stream>>>(x, W1, b1, W2, b2,
                                                  counts, btok, bwv, accb);
    ln_kernel<<<NTOK, 256, 0, stream>>>(x, accb, gamma, beta, (float*)d_out);
}